// Round 3
// baseline (368.686 us; speedup 1.0000x reference)
//
#include <hip/hip_runtime.h>
#include <hip/hip_bf16.h>

// SplitMLP: B=128, C=16, V=32, H=64, O=4, G=10000
// v4: GROUP-STREAMING waves (page-density fix). v0-v3 all walked the batch dim
// (items stride 1.28 MB): every wave touched ~128 distinct MB-spaced pages ->
// measured ~2 outstanding loads/CU, effective load latency in the us range
// (translation-bound, not data-path). v4 transposes the parallelization:
// block = ALL 128 batches x NG=8 consecutive groups (grid 1250); wave w owns
// batch rows [32w,32w+32) forever (fixed small page set) and STREAMS groups
// with unit stride. W1/W2/b1/b2 become one sequential walk per block, shared
// by the 4 in-phase waves (L1/L2 reuse; HBM reads each byte once). Deep
// per-wave software pipeline: convert(g) -> issue b(g) -> issue staging(g+1)
// -> compute(g). Zero barriers. LDS only for wave-private Hb transpose.
// Numerics identical to v0-v3 (same frag math, f32 bias adds, same k-order).

typedef __bf16 v8bf __attribute__((ext_vector_type(8)));
typedef __bf16 v4bf __attribute__((ext_vector_type(4)));
typedef float  v4f  __attribute__((ext_vector_type(4)));

#define B_   128
#define C_   16
#define V_   32
#define H_   64
#define O_   4
#define G_   10000
#define NG   8    // groups per block; grid = G/NG = 1250
#define HS_  72   // Hb stride (elems): 144B -> 16B-aligned, 2-way banks (free)

__device__ __forceinline__ v8bf cvt8(float4 lo, float4 hi) {
  v8bf r;
  r[0] = (__bf16)lo.x; r[1] = (__bf16)lo.y; r[2] = (__bf16)lo.z; r[3] = (__bf16)lo.w;
  r[4] = (__bf16)hi.x; r[5] = (__bf16)hi.y; r[6] = (__bf16)hi.z; r[7] = (__bf16)hi.w;
  return r;
}
__device__ __forceinline__ v8bf gload8(const float* __restrict__ p) {
  const float4* p4 = reinterpret_cast<const float4*>(p);
  return cvt8(p4[0], p4[1]);
}

__global__ __launch_bounds__(256, 2)
void splitmlp_kernel(const float* __restrict__ day,
                     const float* __restrict__ items,
                     const float* __restrict__ W1d,
                     const float* __restrict__ W1v,
                     const float* __restrict__ b1,
                     const float* __restrict__ W2,
                     const float* __restrict__ b2,
                     float* __restrict__ out) {
  __shared__ __bf16 Hb[4][32 * HS_];   // 18,432 B: per-wave h^T [row32][hid64]

  const int t    = threadIdx.x;
  const int w    = t >> 6;
  const int lane = t & 63;
  const int c    = lane & 15;
  const int q    = lane >> 4;
  const int g0   = blockIdx.x * NG;
  const int rbase = w * 32;            // this wave's batch rows [rbase, rbase+32)

  v8bf zf;
#pragma unroll
  for (int i = 0; i < 8; ++i) zf[i] = (__bf16)0.0f;
  const v4f zero = {0.f, 0.f, 0.f, 0.f};

  // ---- day frags: group-invariant, loaded once (rows are pinned per wave) ----
  v8bf dayf[2];
#pragma unroll
  for (int nb = 0; nb < 2; ++nb) {
    const int b = rbase + nb * 16 + c;
    dayf[nb] = (q < 2) ? gload8(day + b * C_ + q * 8) : zf;
  }

  // ---- per-lane streaming pointers (all advance with unit group stride) ----
  // fc1 frag0 (k=q*8): q<2 -> W1d[h][q*8..+8); q>=2 -> W1v[h][(q-2)*8..+8)
  const float* p0 = (q < 2) ? (W1d + (size_t)g0 * (H_ * C_) + c * C_ + q * 8)
                            : (W1v + (size_t)g0 * (H_ * V_) + c * V_ + (q - 2) * 8);
  const int ms0 = (q < 2) ? (16 * C_) : (16 * V_);   // m-tile stride within group
  const int st0 = (q < 2) ? (H_ * C_) : (H_ * V_);   // per-group advance
  // fc1 frag1 (k=32+q*8, q<2 lanes): W1v[h][16+q*8..+8)
  const float* p1 = W1v + (size_t)g0 * (H_ * V_) + c * V_ + 16 + q * 8;
  const float* pw2 = W2 + (size_t)g0 * (O_ * H_) + (c & 3) * H_ + q * 8;
  // items: lane(c,q) reads 8 floats of row (rbase + nb*16 + c), group g.
  // frag0 q>=2 -> items[(q-2)*8]; frag1 q<2 -> items[16+q*8] => ioff=((q+2)&3)*8
  const int ioff = ((q + 2) & 3) * 8;
  const float* pit = items + (size_t)(rbase + c) * (G_ * V_) + (size_t)g0 * V_ + ioff;
  const float* pb1 = b1 + (size_t)g0 * H_;
  const float* pb2 = b2 + (size_t)g0 * O_;

  float4 s0[4][2], s1[4][2], w2s[2][2], it[2][2];

#define ISSUE()                                                        \
  {                                                                    \
    _Pragma("unroll")                                                  \
    for (int m = 0; m < 4; ++m) {                                      \
      const float* p = p0 + m * ms0;                                   \
      s0[m][0] = reinterpret_cast<const float4*>(p)[0];                \
      s0[m][1] = reinterpret_cast<const float4*>(p)[1];                \
    }                                                                  \
    if (q < 2) {                                                       \
      _Pragma("unroll")                                                \
      for (int m = 0; m < 4; ++m) {                                    \
        const float* p = p1 + m * (16 * V_);                           \
        s1[m][0] = reinterpret_cast<const float4*>(p)[0];              \
        s1[m][1] = reinterpret_cast<const float4*>(p)[1];              \
      }                                                                \
    }                                                                  \
    w2s[0][0] = reinterpret_cast<const float4*>(pw2)[0];               \
    w2s[0][1] = reinterpret_cast<const float4*>(pw2)[1];               \
    w2s[1][0] = reinterpret_cast<const float4*>(pw2 + 32)[0];          \
    w2s[1][1] = reinterpret_cast<const float4*>(pw2 + 32)[1];          \
    it[0][0] = reinterpret_cast<const float4*>(pit)[0];                \
    it[0][1] = reinterpret_cast<const float4*>(pit)[1];                \
    {                                                                  \
      const float* pitB = pit + (size_t)16 * (G_ * V_);                \
      it[1][0] = reinterpret_cast<const float4*>(pitB)[0];             \
      it[1][1] = reinterpret_cast<const float4*>(pitB)[1];             \
    }                                                                  \
    p0 += st0; p1 += H_ * V_; pw2 += O_ * H_; pit += V_;               \
  }

  // prologue: loads for g0 in flight
  ISSUE();

#pragma unroll 1
  for (int gi = 0; gi < NG; ++gi) {
    // ---- convert staging(g) -> frags (vmcnt waits happen here) ----
    v8bf wf0[4], wf1[4], w2f[2], icf[2];
#pragma unroll
    for (int m = 0; m < 4; ++m) wf0[m] = cvt8(s0[m][0], s0[m][1]);
#pragma unroll
    for (int m = 0; m < 4; ++m) wf1[m] = (q < 2) ? cvt8(s1[m][0], s1[m][1]) : zf;
    w2f[0] = (c < O_) ? cvt8(w2s[0][0], w2s[0][1]) : zf;
    w2f[1] = (c < O_) ? cvt8(w2s[1][0], w2s[1][1]) : zf;
#pragma unroll
    for (int nb = 0; nb < 2; ++nb) icf[nb] = cvt8(it[nb][0], it[nb][1]);

    // ---- bias loads for g (issued BEFORE next-group staging: FIFO-older,
    //      so epilogue's wait on them does NOT drain the staging loads) ----
    float4 bbv[4];
#pragma unroll
    for (int m = 0; m < 4; ++m)
      bbv[m] = *reinterpret_cast<const float4*>(pb1 + m * 16 + q * 4);
    const float4 b2v = *reinterpret_cast<const float4*>(pb2);
    pb1 += H_; pb2 += O_;

    // ---- issue staging loads for g+1 (latency covered by compute below) ----
    if (gi < NG - 1) ISSUE();

    // ---- fc1: h^T[64][32 rows] = W1 @ A^T ----
    v8bf blv[2], bhv[2];
#pragma unroll
    for (int nb = 0; nb < 2; ++nb) {
      blv[nb] = (q < 2) ? dayf[nb] : icf[nb];
      bhv[nb] = (q < 2) ? icf[nb] : zf;
    }
    v4f acc[4][2];
#pragma unroll
    for (int m = 0; m < 4; ++m)
#pragma unroll
      for (int nb = 0; nb < 2; ++nb) acc[m][nb] = zero;
#pragma unroll
    for (int m = 0; m < 4; ++m)
#pragma unroll
      for (int nb = 0; nb < 2; ++nb) {
        acc[m][nb] = __builtin_amdgcn_mfma_f32_16x16x32_bf16(wf0[m], blv[nb], acc[m][nb], 0, 0, 0);
        acc[m][nb] = __builtin_amdgcn_mfma_f32_16x16x32_bf16(wf1[m], bhv[nb], acc[m][nb], 0, 0, 0);
      }

    // ---- epilogue: +b1 (f32), ReLU, packed b64 -> wave-private Hb ----
#pragma unroll
    for (int m = 0; m < 4; ++m)
#pragma unroll
      for (int nb = 0; nb < 2; ++nb) {
        v4bf hv;
        hv[0] = (__bf16)fmaxf(acc[m][nb][0] + bbv[m].x, 0.f);
        hv[1] = (__bf16)fmaxf(acc[m][nb][1] + bbv[m].y, 0.f);
        hv[2] = (__bf16)fmaxf(acc[m][nb][2] + bbv[m].z, 0.f);
        hv[3] = (__bf16)fmaxf(acc[m][nb][3] + bbv[m].w, 0.f);
        *reinterpret_cast<v4bf*>(&Hb[w][(nb * 16 + c) * HS_ + m * 16 + q * 4]) = hv;
      }

    // ---- fc2: y^T = W2(pad16) @ h^T ----
    v4f y[2] = {zero, zero};
#pragma unroll
    for (int kt = 0; kt < 2; ++kt)
#pragma unroll
      for (int nb = 0; nb < 2; ++nb) {
        const v8bf hf = *reinterpret_cast<const v8bf*>(&Hb[w][(nb * 16 + c) * HS_ + kt * 32 + q * 8]);
        y[nb] = __builtin_amdgcn_mfma_f32_16x16x32_bf16(w2f[kt], hf, y[nb], 0, 0, 0);
      }

    // ---- store: q==0 lanes hold o=0..3 for batch (rbase+nb*16+c) ----
    if (q == 0) {
#pragma unroll
      for (int nb = 0; nb < 2; ++nb) {
        float4 o;
        o.x = y[nb][0] + b2v.x;
        o.y = y[nb][1] + b2v.y;
        o.z = y[nb][2] + b2v.z;
        o.w = y[nb][3] + b2v.w;
        *reinterpret_cast<float4*>(out + (size_t)(rbase + nb * 16 + c) * (G_ * O_) +
                                   (size_t)(g0 + gi) * O_) = o;
      }
    }
  }
#undef ISSUE
}

extern "C" void kernel_launch(void* const* d_in, const int* in_sizes, int n_in,
                              void* d_out, int out_size, void* d_ws, size_t ws_size,
                              hipStream_t stream) {
  const float* day   = (const float*)d_in[0];
  const float* items = (const float*)d_in[1];
  const float* W1d   = (const float*)d_in[2];
  const float* W1v   = (const float*)d_in[3];
  const float* b1    = (const float*)d_in[4];
  const float* W2    = (const float*)d_in[5];
  const float* b2    = (const float*)d_in[6];
  float* out = (float*)d_out;
  splitmlp_kernel<<<G_ / NG, 256, 0, stream>>>(day, items, W1d, W1v, b1, W2, b2, out);
}